// Round 8
// baseline (140.485 us; speedup 1.0000x reference)
//
#include <hip/hip_runtime.h>

typedef float v2f __attribute__((ext_vector_type(2)));
#define PKFMA(a,b,c) __builtin_elementwise_fma((a),(b),(c))
#define PKMAX(a,b)   __builtin_elementwise_max((a),(b))
static __device__ __forceinline__ v2f vsplat(float s) { return (v2f){s, s}; }
static __device__ __forceinline__ v2f vmk(float a, float b) { return (v2f){a, b}; }
static __device__ __forceinline__ v2f shfl_xor_v2(v2f x, int m) {
    double d = __builtin_bit_cast(double, x);
    d = __shfl_xor(d, m, 64);
    return __builtin_bit_cast(v2f, d);
}

// ---------------- workspace float offsets ----------------
#define WS_WQC   0        // wq@w_iq          128x128 row-major
#define WS_WKC   16384    // wk@w_ik          128x128 row-major
#define WS_WVC   32768    // wv@w_iv          128x128 row-major
#define WS_MOW   49152    // mha_out_w@out_w  128x128 row-major
#define WS_GQ    65536    // [64][128]: cols 0..63 G, 64..95 Gs, 96..127 Gd
#define WS_G0Q   73728    // [128] biases in same col order
#define WS_FALL  73856    // [128][128]: rows 0..31 Fsp, 32..63 Fdv, 64..127 Fhid
#define WS_FB    90240    // [128]
#define WS_HID   90368    // [128 batches][64][64] relu(hs@w_hid+b_hid)
#define WS_NEED_HID_BYTES ((size_t)(90368 + 128*64*64) * 4)

// P1: weight products (+ per-batch hid into ws when workspace allows)
__global__ __launch_bounds__(256) void precompute1(
    const float* __restrict__ wq, const float* __restrict__ wk,
    const float* __restrict__ wv, const float* __restrict__ in_proj_w,
    const float* __restrict__ mha_out_w, const float* __restrict__ out_w,
    const float* __restrict__ hs, const float* __restrict__ w_hid,
    const float* __restrict__ b_hid, float* __restrict__ ws)
{
    __shared__ __align__(16) float sbuf[4224];
    const int tid = threadIdx.x;

    if (blockIdx.x < 256) {
        const int mat  = blockIdx.x >> 6;
        const int rp   = blockIdx.x & 63;
        const int rsel = tid >> 7;
        const int col  = tid & 127;
        const int r    = 2 * rp + rsel;
        const float* A; const float* Bm; int ldb; float* C;
        if (mat == 0)      { A = wq;        Bm = in_proj_w;       ldb = 384; C = ws + WS_WQC; }
        else if (mat == 1) { A = wk;        Bm = in_proj_w + 128; ldb = 384; C = ws + WS_WKC; }
        else if (mat == 2) { A = wv;        Bm = in_proj_w + 256; ldb = 384; C = ws + WS_WVC; }
        else               { A = mha_out_w; Bm = out_w;           ldb = 128; C = ws + WS_MOW; }
        sbuf[tid] = A[r * 128 + col];
        __syncthreads();
        float acc = 0.f;
        #pragma unroll 8
        for (int d = 0; d < 128; ++d) acc = fmaf(sbuf[rsel * 128 + d], Bm[d * ldb + col], acc);
        C[r * 128 + col] = acc;
    } else {
        const int b2 = blockIdx.x - 256;
        const int b = b2 >> 1, half = b2 & 1;
        const float4* src = (const float4*)(hs + b * 8192 + half * 4096);
        for (int k = tid; k < 1024; k += 256) {
            const int row = k >> 5, c = k & 31;
            *(float4*)&sbuf[row * 132 + 4 * c] = src[k];
        }
        __syncthreads();
        const int ty = tid >> 4, tx = tid & 15;
        float a0c[4] = {0,0,0,0}, a1c[4] = {0,0,0,0};
        for (int d0 = 0; d0 < 128; d0 += 4) {
            const float4 a0 = *(const float4*)&sbuf[(2*ty+0)*132 + d0];
            const float4 a1 = *(const float4*)&sbuf[(2*ty+1)*132 + d0];
            const float* a0p = (const float*)&a0;
            const float* a1p = (const float*)&a1;
            #pragma unroll
            for (int dd = 0; dd < 4; ++dd) {
                const float4 w4 = *(const float4*)&w_hid[(d0+dd)*64 + 4*tx];
                a0c[0] = fmaf(a0p[dd], w4.x, a0c[0]); a0c[1] = fmaf(a0p[dd], w4.y, a0c[1]);
                a0c[2] = fmaf(a0p[dd], w4.z, a0c[2]); a0c[3] = fmaf(a0p[dd], w4.w, a0c[3]);
                a1c[0] = fmaf(a1p[dd], w4.x, a1c[0]); a1c[1] = fmaf(a1p[dd], w4.y, a1c[1]);
                a1c[2] = fmaf(a1p[dd], w4.z, a1c[2]); a1c[3] = fmaf(a1p[dd], w4.w, a1c[3]);
            }
        }
        const float4 bh = *(const float4*)&b_hid[4*tx];
        float* dst = ws + WS_HID + b * 4096 + (32*half + 2*ty) * 64 + 4*tx;
        *(float4*)dst        = make_float4(fmaxf(a0c[0]+bh.x,0.f), fmaxf(a0c[1]+bh.y,0.f),
                                           fmaxf(a0c[2]+bh.z,0.f), fmaxf(a0c[3]+bh.w,0.f));
        *(float4*)(dst + 64) = make_float4(fmaxf(a1c[0]+bh.x,0.f), fmaxf(a1c[1]+bh.y,0.f),
                                           fmaxf(a1c[2]+bh.z,0.f), fmaxf(a1c[3]+bh.w,0.f));
    }
}

// P2: derived fused tensors GQ / g0q / F_all / fb (float4 row reads)
__global__ __launch_bounds__(128) void precompute2(
    const float* __restrict__ b_sp, const float* __restrict__ b_vel,
    const float* __restrict__ in_proj_b, const float* __restrict__ mha_out_b,
    const float* __restrict__ out_w, const float* __restrict__ out_b,
    float* __restrict__ ws)
{
    const float* Wqc = ws + WS_WQC;
    const float* Wkc = ws + WS_WKC;
    const float* Wvc = ws + WS_WVC;
    const float* Mow = ws + WS_MOW;
    const int bid = blockIdx.x, tid = threadIdx.x;
    __shared__ __align__(16) float sa[128];

    if (bid < 64) {
        const int k = bid;
        sa[tid] = Wqc[(32 + k) * 128 + tid];
        __syncthreads();
        const int j = tid;
        const int pj = (j < 64) ? 32 + j : ((j < 96) ? j - 64 : j);
        const float* brow = Wkc + pj * 128;
        float acc = 0.f;
        #pragma unroll 8
        for (int d = 0; d < 128; d += 4) {
            const float4 a4 = *(const float4*)&sa[d];
            const float4 b4 = *(const float4*)&brow[d];
            acc = fmaf(a4.x, b4.x, fmaf(a4.y, b4.y, fmaf(a4.z, b4.z, fmaf(a4.w, b4.w, acc))));
        }
        ws[WS_GQ + k * 128 + j] = acc;
    } else if (bid < 192) {
        const int k2 = bid - 64;
        const int srcRow = (k2 < 32) ? k2 : ((k2 < 64) ? 96 + (k2 - 32) : 32 + (k2 - 64));
        sa[tid] = Wvc[srcRow * 128 + tid];
        __syncthreads();
        float acc = 0.f;
        #pragma unroll 8
        for (int m = 0; m < 128; ++m) acc = fmaf(sa[m], Mow[m * 128 + tid], acc);
        ws[WS_FALL + k2 * 128 + tid] = acc;
    } else if (bid == 192) {
        float acc = out_b[tid];
        #pragma unroll 8
        for (int m = 0; m < 128; ++m) {
            acc = fmaf(in_proj_b[256 + m], Mow[m * 128 + tid], acc);
            acc = fmaf(mha_out_b[m], out_w[m * 128 + tid], acc);
        }
        ws[WS_FB + tid] = acc;
    } else {
        float qc = in_proj_b[tid];  // b_iq
        #pragma unroll 4
        for (int s = 0; s < 32; ++s) {
            qc = fmaf(fmaxf(b_sp[s], 0.f),  Wqc[s * 128 + tid], qc);
            qc = fmaf(fmaxf(b_vel[s], 0.f), Wqc[(96 + s) * 128 + tid], qc);
        }
        sa[tid] = qc;
        __syncthreads();
        const int j = tid;
        const int pj = (j < 64) ? 32 + j : ((j < 96) ? j - 64 : j);
        const float* brow = Wkc + pj * 128;
        float acc = 0.f;
        #pragma unroll 8
        for (int d = 0; d < 128; d += 4) {
            const float4 a4 = *(const float4*)&sa[d];
            const float4 b4 = *(const float4*)&brow[d];
            acc = fmaf(a4.x, b4.x, fmaf(a4.y, b4.y, fmaf(a4.z, b4.z, fmaf(a4.w, b4.w, acc))));
        }
        ws[WS_G0Q + j] = acc;
    }
}

// ---------------- attn_main v5: 2 rows/wave, packed fp32, 16 waves/CU ----------------
// LDS floats: s_hid 64x66 (4224) | s_obs 256 | per-wave 384:
//   tt[2][64] (t -> ssp|sdv), qq[2][64] (qs|qd -> ah), aa[64][2] (attn)
#define L_OBS  4224
#define L_WV   4480
// total 4480 + 4*384 = 6016 floats = 24.1 KB; grid 1024 -> 4 blocks/CU = 16 waves/CU

template <bool HIDWS>
__global__ __launch_bounds__(256) void attn_main(
    const float* __restrict__ hs, const float* __restrict__ obs1,
    const float* __restrict__ obs2,
    const float* __restrict__ w_sp, const float* __restrict__ b_sp,
    const float* __restrict__ w_vel, const float* __restrict__ b_vel,
    const float* __restrict__ w_hid, const float* __restrict__ b_hid,
    const float* __restrict__ ws, float* __restrict__ out)
{
    const int tid = threadIdx.x;
    const int l   = tid & 63;
    const int w   = tid >> 6;
    const int b   = blockIdx.x >> 3;
    const int i0  = (blockIdx.x & 7) * 8;
    const int rg0 = i0 + 2 * w;          // rows rg0, rg0+1

    const float* GQ   = ws + WS_GQ;
    const float* g0q  = ws + WS_G0Q;
    const float* Fall = ws + WS_FALL;
    const float* fbv  = ws + WS_FB;

    __shared__ __align__(16) float smem[6016];
    float* const s_hid = smem;                 // stride 66
    float* const s_obs = smem + L_OBS;         // [j][4] = {o2x,o2y,vx,vy}
    float* const tt = smem + L_WV + w * 384;         // [r][64]
    float* const qq = smem + L_WV + w * 384 + 128;   // [r][qs32|qd32]
    float* const aa = smem + L_WV + w * 384 + 256;   // [j][2]

    // ---- staging ----
    if (tid < 64) {
        const int g = b * 64 + tid;
        const float2 o2 = ((const float2*)obs2)[g];
        const float2 o1 = ((const float2*)obs1)[g];
        *(float4*)&s_obs[tid * 4] = make_float4(o2.x, o2.y, o2.x - o1.x, o2.y - o1.y);
    }
    if (HIDWS) {
        const float4* src = (const float4*)(ws + WS_HID + b * 4096);
        #pragma unroll
        for (int k = tid; k < 1024; k += 256) {
            const int row = k >> 4, c4 = (k & 15) * 4;
            const float4 v = src[k];
            *(v2f*)&s_hid[row * 66 + c4]     = vmk(v.x, v.y);
            *(v2f*)&s_hid[row * 66 + c4 + 2] = vmk(v.z, v.w);
        }
    } else {
        const int r = tid >> 2, qseg = (tid & 3) * 16;
        float acc[16];
        #pragma unroll
        for (int c = 0; c < 16; ++c) acc[c] = b_hid[qseg + c];
        for (int k = 0; k < 128; ++k) {
            const float a = hs[b * 8192 + r * 128 + k];
            #pragma unroll
            for (int c4 = 0; c4 < 4; ++c4) {
                const float4 w4 = *(const float4*)&w_hid[k * 64 + qseg + 4 * c4];
                acc[4*c4+0] = fmaf(a, w4.x, acc[4*c4+0]);
                acc[4*c4+1] = fmaf(a, w4.y, acc[4*c4+1]);
                acc[4*c4+2] = fmaf(a, w4.z, acc[4*c4+2]);
                acc[4*c4+3] = fmaf(a, w4.w, acc[4*c4+3]);
            }
        }
        #pragma unroll
        for (int c = 0; c < 16; c += 2)
            *(v2f*)&s_hid[r * 66 + qseg + c] =
                vmk(fmaxf(acc[c], 0.f), fmaxf(acc[c+1], 0.f));
    }
    __syncthreads();
    // ---- wave-private phases below (same-wave LDS ordering) ----

    // ---- phase 3: cols {2l,2l+1} of [t | qs | qd] = hid[row] @ GQ + g0q ----
    {
        const v2f bias = *(const v2f*)&g0q[2 * l];
        v2f acc0 = bias, acc1 = bias;
        for (int k0 = 0; k0 < 64; k0 += 2) {
            const v2f g0 = *(const v2f*)&GQ[k0 * 128 + 2 * l];
            const v2f g1 = *(const v2f*)&GQ[(k0 + 1) * 128 + 2 * l];
            const v2f h0 = *(const v2f*)&s_hid[(rg0 + 0) * 66 + k0];
            const v2f h1 = *(const v2f*)&s_hid[(rg0 + 1) * 66 + k0];
            acc0 = PKFMA(vsplat(h0.x), g0, PKFMA(vsplat(h0.y), g1, acc0));
            acc1 = PKFMA(vsplat(h1.x), g0, PKFMA(vsplat(h1.y), g1, acc1));
        }
        if (l < 32) {
            const int c = 2 * l;
            *(v2f*)&tt[c]      = acc0;
            *(v2f*)&tt[64 + c] = acc1;
        } else {
            const int c = 2 * l - 64;
            *(v2f*)&qq[c]      = acc0;
            *(v2f*)&qq[64 + c] = acc1;
        }
    }

    // ---- phase 4: sc[r] = t[r] . hid[l] ----
    float sc0, sc1;
    {
        v2f s0 = (v2f){0.f,0.f}, s1 = s0;
        const float* hl = &s_hid[l * 66];
        for (int c0 = 0; c0 < 64; c0 += 2) {
            const v2f h2 = *(const v2f*)&hl[c0];
            s0 = PKFMA(*(const v2f*)&tt[c0],      h2, s0);
            s1 = PKFMA(*(const v2f*)&tt[64 + c0], h2, s1);
        }
        sc0 = s0.x + s0.y;
        sc1 = s1.x + s1.y;
    }

    // ---- phase 5: scores + packed softmax; attn -> aa[j][2] ----
    {
        const float4 oj  = *(const float4*)&s_obs[4 * l];
        const float4 oiA = *(const float4*)&s_obs[4 * rg0];
        const float4 oiB = *(const float4*)&s_obs[4 * (rg0 + 1)];
        const float rxA = oj.x - oiA.x, ryA = oj.y - oiA.y;
        const float dxA = (oj.z - oiA.z) * 4.f, dyA = (oj.w - oiA.w) * 4.f;
        const float rxB = oj.x - oiB.x, ryB = oj.y - oiB.y;
        const float dxB = (oj.z - oiB.z) * 4.f, dyB = (oj.w - oiB.w) * 4.f;
        v2f accA = (v2f){0.f, 0.f}, accB = accA;
        for (int s0 = 0; s0 < 32; s0 += 2) {
            const v2f w0p = *(const v2f*)&w_sp[s0];
            const v2f w1p = *(const v2f*)&w_sp[32 + s0];
            const v2f bsp = *(const v2f*)&b_sp[s0];
            const v2f u0p = *(const v2f*)&w_vel[s0];
            const v2f u1p = *(const v2f*)&w_vel[32 + s0];
            const v2f bvp = *(const v2f*)&b_vel[s0];
            const v2f qsA = *(const v2f*)&qq[s0];
            const v2f qsB = *(const v2f*)&qq[64 + s0];
            const v2f qdA = *(const v2f*)&qq[32 + s0];
            const v2f qdB = *(const v2f*)&qq[96 + s0];
            const v2f espA = PKMAX(PKFMA(vsplat(rxA), w0p, PKFMA(vsplat(ryA), w1p, bsp)), vsplat(0.f));
            const v2f edvA = PKMAX(PKFMA(vsplat(dxA), u0p, PKFMA(vsplat(dyA), u1p, bvp)), vsplat(0.f));
            accA = PKFMA(qsA, espA, PKFMA(qdA, edvA, accA));
            const v2f espB = PKMAX(PKFMA(vsplat(rxB), w0p, PKFMA(vsplat(ryB), w1p, bsp)), vsplat(0.f));
            const v2f edvB = PKMAX(PKFMA(vsplat(dxB), u0p, PKFMA(vsplat(dyB), u1p, bvp)), vsplat(0.f));
            accB = PKFMA(qsB, espB, PKFMA(qdB, edvB, accB));
        }
        const float scale = 0.08838834764831845f;  // 1/sqrt(128)
        v2f p = vmk((sc0 + accA.x + accA.y) * scale,
                    (sc1 + accB.x + accB.y) * scale);
        v2f m = p;
        #pragma unroll
        for (int off = 32; off > 0; off >>= 1) m = PKMAX(m, shfl_xor_v2(m, off));
        v2f e = vmk(__expf(p.x - m.x), __expf(p.y - m.y));
        v2f u = e;
        #pragma unroll
        for (int off = 32; off > 0; off >>= 1) u = u + shfl_xor_v2(u, off);
        *(v2f*)&aa[2 * l] = vmk(e.x / u.x, e.y / u.y);
    }

    // ---- phase 6a: pooled embeds -> tt[r] = [ssp 0..31 | sdv 32..63] ----
    {
        const int r = l >> 5, s = l & 31;    // lane: row r, slot s (sp and dv jointly)
        const v2f w0p = vmk(w_sp[s],      w_vel[s]);
        const v2f w1p = vmk(w_sp[32 + s], w_vel[32 + s]);
        const v2f bp  = vmk(b_sp[s],      b_vel[s]);
        const float4 oi = *(const float4*)&s_obs[4 * (rg0 + r)];
        v2f acc = (v2f){0.f, 0.f};
        for (int j = 0; j < 64; ++j) {
            const float a = aa[2 * j + r];
            const float4 o4 = *(const float4*)&s_obs[4 * j];
            const float rx = o4.x - oi.x, ry = o4.y - oi.y;
            const float dx = (o4.z - oi.z) * 4.f, dy = (o4.w - oi.w) * 4.f;
            const v2f uv = PKMAX(PKFMA(vmk(rx, dx), w0p,
                                 PKFMA(vmk(ry, dy), w1p, bp)), vsplat(0.f));
            acc = PKFMA(vsplat(a), uv, acc);
        }
        tt[r * 64 + s]      = acc.x;   // ssp
        tt[r * 64 + 32 + s] = acc.y;   // sdv
    }

    // ---- phase 6b: ah[r][l] = attn[r] @ hid -> qq[r][l] ----
    {
        float ah0 = 0.f, ah1 = 0.f;
        for (int j = 0; j < 64; j += 2) {
            const float4 a2 = *(const float4*)&aa[2 * j];   // {a_j^0, a_j^1, a_{j+1}^0, a_{j+1}^1}
            const float h0 = s_hid[j * 66 + l];
            const float h1 = s_hid[(j + 1) * 66 + l];
            ah0 = fmaf(a2.x, h0, fmaf(a2.z, h1, ah0));
            ah1 = fmaf(a2.y, h0, fmaf(a2.w, h1, ah1));
        }
        qq[l]      = ah0;
        qq[64 + l] = ah1;
    }

    // ---- phase 7: out = [ssp|sdv] @ Fall[0:64] + ah @ Fall[64:128] + fb ----
    {
        const v2f fb2 = *(const v2f*)&fbv[2 * l];
        v2f o0 = fb2, o1 = fb2;
        for (int k = 0; k < 64; k += 2) {
            const v2f f0 = *(const v2f*)&Fall[k * 128 + 2 * l];
            const v2f f1 = *(const v2f*)&Fall[(k + 1) * 128 + 2 * l];
            const v2f A0 = *(const v2f*)&tt[k];
            const v2f A1 = *(const v2f*)&tt[64 + k];
            o0 = PKFMA(vsplat(A0.x), f0, PKFMA(vsplat(A0.y), f1, o0));
            o1 = PKFMA(vsplat(A1.x), f0, PKFMA(vsplat(A1.y), f1, o1));
        }
        for (int k = 0; k < 64; k += 2) {
            const v2f f0 = *(const v2f*)&Fall[(64 + k) * 128 + 2 * l];
            const v2f f1 = *(const v2f*)&Fall[(65 + k) * 128 + 2 * l];
            const v2f A0 = *(const v2f*)&qq[k];
            const v2f A1 = *(const v2f*)&qq[64 + k];
            o0 = PKFMA(vsplat(A0.x), f0, PKFMA(vsplat(A0.y), f1, o0));
            o1 = PKFMA(vsplat(A1.x), f0, PKFMA(vsplat(A1.y), f1, o1));
        }
        const int gr = (b * 64 + rg0) * 128 + 2 * l;
        *(v2f*)&out[gr]       = o0;
        *(v2f*)&out[gr + 128] = o1;
    }
}

extern "C" void kernel_launch(void* const* d_in, const int* in_sizes, int n_in,
                              void* d_out, int out_size, void* d_ws, size_t ws_size,
                              hipStream_t stream) {
    const float* hs        = (const float*)d_in[0];
    const float* obs1      = (const float*)d_in[1];
    const float* obs2      = (const float*)d_in[2];
    const float* w_sp      = (const float*)d_in[3];
    const float* b_sp      = (const float*)d_in[4];
    const float* w_vel     = (const float*)d_in[5];
    const float* b_vel     = (const float*)d_in[6];
    const float* w_hid     = (const float*)d_in[7];
    const float* b_hid     = (const float*)d_in[8];
    const float* wq        = (const float*)d_in[9];
    const float* wk        = (const float*)d_in[10];
    const float* wv        = (const float*)d_in[11];
    const float* in_proj_w = (const float*)d_in[12];
    const float* in_proj_b = (const float*)d_in[13];
    const float* mha_out_w = (const float*)d_in[14];
    const float* mha_out_b = (const float*)d_in[15];
    const float* out_w     = (const float*)d_in[16];
    const float* out_b     = (const float*)d_in[17];
    float* ws  = (float*)d_ws;
    float* out = (float*)d_out;

    const bool hidws = (ws_size >= WS_NEED_HID_BYTES);

    precompute1<<<hidws ? 512 : 256, 256, 0, stream>>>(
        wq, wk, wv, in_proj_w, mha_out_w, out_w, hs, w_hid, b_hid, ws);
    precompute2<<<194, 128, 0, stream>>>(
        b_sp, b_vel, in_proj_b, mha_out_b, out_w, out_b, ws);
    if (hidws) {
        attn_main<true><<<1024, 256, 0, stream>>>(hs, obs1, obs2, w_sp, b_sp, w_vel, b_vel,
                                                  w_hid, b_hid, ws, out);
    } else {
        attn_main<false><<<1024, 256, 0, stream>>>(hs, obs1, obs2, w_sp, b_sp, w_vel, b_vel,
                                                   w_hid, b_hid, ws, out);
    }
}

// Round 9
// 127.962 us; speedup vs baseline: 1.0979x; 1.0979x over previous
//
#include <hip/hip_runtime.h>

typedef float v2f __attribute__((ext_vector_type(2)));
#define PKFMA(a,b,c) __builtin_elementwise_fma((a),(b),(c))
#define PKMAX(a,b)   __builtin_elementwise_max((a),(b))
static __device__ __forceinline__ v2f vsplat(float s) { return (v2f){s, s}; }
static __device__ __forceinline__ v2f vmk(float a, float b) { return (v2f){a, b}; }
static __device__ __forceinline__ v2f shfl_xor_v2(v2f x, int m) {
    double d = __builtin_bit_cast(double, x);
    d = __shfl_xor(d, m, 64);
    return __builtin_bit_cast(v2f, d);
}

// ---------------- workspace float offsets ----------------
#define WS_WQC   0        // wq@w_iq          128x128 row-major
#define WS_WKC   16384    // wk@w_ik          128x128 row-major
#define WS_WVC   32768    // wv@w_iv          128x128 row-major
#define WS_MOW   49152    // mha_out_w@out_w  128x128 row-major
#define WS_GQ    65536    // [64][128]: cols 0..63 G, 64..95 Gs, 96..127 Gd
#define WS_G0Q   73728    // [128] biases in same col order
#define WS_FALL  73856    // [128][128]: rows 0..31 Fsp, 32..63 Fdv, 64..127 Fhid
#define WS_FB    90240    // [128]
#define WS_HID   90368    // [128 batches][64][64] relu(hs@w_hid+b_hid)
#define WS_NEED_HID_BYTES ((size_t)(90368 + 128*64*64) * 4)

// P1: weight products (+ per-batch hid into ws when workspace allows)
__global__ __launch_bounds__(256) void precompute1(
    const float* __restrict__ wq, const float* __restrict__ wk,
    const float* __restrict__ wv, const float* __restrict__ in_proj_w,
    const float* __restrict__ mha_out_w, const float* __restrict__ out_w,
    const float* __restrict__ hs, const float* __restrict__ w_hid,
    const float* __restrict__ b_hid, float* __restrict__ ws)
{
    __shared__ __align__(16) float sbuf[4224];
    const int tid = threadIdx.x;

    if (blockIdx.x < 256) {
        const int mat  = blockIdx.x >> 6;
        const int rp   = blockIdx.x & 63;
        const int rsel = tid >> 7;
        const int col  = tid & 127;
        const int r    = 2 * rp + rsel;
        const float* A; const float* Bm; int ldb; float* C;
        if (mat == 0)      { A = wq;        Bm = in_proj_w;       ldb = 384; C = ws + WS_WQC; }
        else if (mat == 1) { A = wk;        Bm = in_proj_w + 128; ldb = 384; C = ws + WS_WKC; }
        else if (mat == 2) { A = wv;        Bm = in_proj_w + 256; ldb = 384; C = ws + WS_WVC; }
        else               { A = mha_out_w; Bm = out_w;           ldb = 128; C = ws + WS_MOW; }
        sbuf[tid] = A[r * 128 + col];
        __syncthreads();
        float acc = 0.f;
        #pragma unroll 8
        for (int d = 0; d < 128; ++d) acc = fmaf(sbuf[rsel * 128 + d], Bm[d * ldb + col], acc);
        C[r * 128 + col] = acc;
    } else {
        const int b2 = blockIdx.x - 256;
        const int b = b2 >> 1, half = b2 & 1;
        const float4* src = (const float4*)(hs + b * 8192 + half * 4096);
        for (int k = tid; k < 1024; k += 256) {
            const int row = k >> 5, c = k & 31;
            *(float4*)&sbuf[row * 132 + 4 * c] = src[k];
        }
        __syncthreads();
        const int ty = tid >> 4, tx = tid & 15;
        float a0c[4] = {0,0,0,0}, a1c[4] = {0,0,0,0};
        for (int d0 = 0; d0 < 128; d0 += 4) {
            const float4 a0 = *(const float4*)&sbuf[(2*ty+0)*132 + d0];
            const float4 a1 = *(const float4*)&sbuf[(2*ty+1)*132 + d0];
            const float* a0p = (const float*)&a0;
            const float* a1p = (const float*)&a1;
            #pragma unroll
            for (int dd = 0; dd < 4; ++dd) {
                const float4 w4 = *(const float4*)&w_hid[(d0+dd)*64 + 4*tx];
                a0c[0] = fmaf(a0p[dd], w4.x, a0c[0]); a0c[1] = fmaf(a0p[dd], w4.y, a0c[1]);
                a0c[2] = fmaf(a0p[dd], w4.z, a0c[2]); a0c[3] = fmaf(a0p[dd], w4.w, a0c[3]);
                a1c[0] = fmaf(a1p[dd], w4.x, a1c[0]); a1c[1] = fmaf(a1p[dd], w4.y, a1c[1]);
                a1c[2] = fmaf(a1p[dd], w4.z, a1c[2]); a1c[3] = fmaf(a1p[dd], w4.w, a1c[3]);
            }
        }
        const float4 bh = *(const float4*)&b_hid[4*tx];
        float* dst = ws + WS_HID + b * 4096 + (32*half + 2*ty) * 64 + 4*tx;
        *(float4*)dst        = make_float4(fmaxf(a0c[0]+bh.x,0.f), fmaxf(a0c[1]+bh.y,0.f),
                                           fmaxf(a0c[2]+bh.z,0.f), fmaxf(a0c[3]+bh.w,0.f));
        *(float4*)(dst + 64) = make_float4(fmaxf(a1c[0]+bh.x,0.f), fmaxf(a1c[1]+bh.y,0.f),
                                           fmaxf(a1c[2]+bh.z,0.f), fmaxf(a1c[3]+bh.w,0.f));
    }
}

// P2: derived fused tensors GQ / g0q / F_all / fb (float4 row reads)
__global__ __launch_bounds__(128) void precompute2(
    const float* __restrict__ b_sp, const float* __restrict__ b_vel,
    const float* __restrict__ in_proj_b, const float* __restrict__ mha_out_b,
    const float* __restrict__ out_w, const float* __restrict__ out_b,
    float* __restrict__ ws)
{
    const float* Wqc = ws + WS_WQC;
    const float* Wkc = ws + WS_WKC;
    const float* Wvc = ws + WS_WVC;
    const float* Mow = ws + WS_MOW;
    const int bid = blockIdx.x, tid = threadIdx.x;
    __shared__ __align__(16) float sa[128];

    if (bid < 64) {
        const int k = bid;
        sa[tid] = Wqc[(32 + k) * 128 + tid];
        __syncthreads();
        const int j = tid;
        const int pj = (j < 64) ? 32 + j : ((j < 96) ? j - 64 : j);
        const float* brow = Wkc + pj * 128;
        float acc = 0.f;
        #pragma unroll 8
        for (int d = 0; d < 128; d += 4) {
            const float4 a4 = *(const float4*)&sa[d];
            const float4 b4 = *(const float4*)&brow[d];
            acc = fmaf(a4.x, b4.x, fmaf(a4.y, b4.y, fmaf(a4.z, b4.z, fmaf(a4.w, b4.w, acc))));
        }
        ws[WS_GQ + k * 128 + j] = acc;
    } else if (bid < 192) {
        const int k2 = bid - 64;
        const int srcRow = (k2 < 32) ? k2 : ((k2 < 64) ? 96 + (k2 - 32) : 32 + (k2 - 64));
        sa[tid] = Wvc[srcRow * 128 + tid];
        __syncthreads();
        float acc = 0.f;
        #pragma unroll 8
        for (int m = 0; m < 128; ++m) acc = fmaf(sa[m], Mow[m * 128 + tid], acc);
        ws[WS_FALL + k2 * 128 + tid] = acc;
    } else if (bid == 192) {
        float acc = out_b[tid];
        #pragma unroll 8
        for (int m = 0; m < 128; ++m) {
            acc = fmaf(in_proj_b[256 + m], Mow[m * 128 + tid], acc);
            acc = fmaf(mha_out_b[m], out_w[m * 128 + tid], acc);
        }
        ws[WS_FB + tid] = acc;
    } else {
        float qc = in_proj_b[tid];  // b_iq
        #pragma unroll 4
        for (int s = 0; s < 32; ++s) {
            qc = fmaf(fmaxf(b_sp[s], 0.f),  Wqc[s * 128 + tid], qc);
            qc = fmaf(fmaxf(b_vel[s], 0.f), Wqc[(96 + s) * 128 + tid], qc);
        }
        sa[tid] = qc;
        __syncthreads();
        const int j = tid;
        const int pj = (j < 64) ? 32 + j : ((j < 96) ? j - 64 : j);
        const float* brow = Wkc + pj * 128;
        float acc = 0.f;
        #pragma unroll 8
        for (int d = 0; d < 128; d += 4) {
            const float4 a4 = *(const float4*)&sa[d];
            const float4 b4 = *(const float4*)&brow[d];
            acc = fmaf(a4.x, b4.x, fmaf(a4.y, b4.y, fmaf(a4.z, b4.z, fmaf(a4.w, b4.w, acc))));
        }
        ws[WS_G0Q + j] = acc;
    }
}

// ---------------- attn_main v4: 4 rows/wave, packed fp32, one barrier ----------------
// LDS floats: s_hid 64x66 (4224) | s_obs 256 | per-wave 768:
//   tt[4][64] (t -> ssp|sdv), qq[4][64] (qs|qd -> ah), aa[64][4] (attn)
// Rows/wave = 4 is the measured optimum: 2 rows/wave doubles per-wave GQ/Fall
// streaming (393 MB L2) and regressed to 140 µs; 4 rows = 196 MB, 128.9 µs.
#define L_OBS  4224
#define L_WV   4480
// total 4480 + 4*768 = 7552 floats = 30.2 KB

template <bool HIDWS>
__global__ __launch_bounds__(256) void attn_main(
    const float* __restrict__ hs, const float* __restrict__ obs1,
    const float* __restrict__ obs2,
    const float* __restrict__ w_sp, const float* __restrict__ b_sp,
    const float* __restrict__ w_vel, const float* __restrict__ b_vel,
    const float* __restrict__ w_hid, const float* __restrict__ b_hid,
    const float* __restrict__ ws, float* __restrict__ out)
{
    const int tid = threadIdx.x;
    const int l   = tid & 63;
    const int w   = tid >> 6;
    const int b   = blockIdx.x >> 2;
    const int i0  = (blockIdx.x & 3) * 16;
    const int rg0 = i0 + 4 * w;          // 4 rows: rg0..rg0+3

    const float* GQ   = ws + WS_GQ;
    const float* g0q  = ws + WS_G0Q;
    const float* Fall = ws + WS_FALL;
    const float* fbv  = ws + WS_FB;

    __shared__ __align__(16) float smem[7552];
    float* const s_hid = smem;                 // stride 66
    float* const s_obs = smem + L_OBS;         // [j][4] = {o2x,o2y,vx,vy}
    float* const tt = smem + L_WV + w * 768;         // [r][64]
    float* const qq = smem + L_WV + w * 768 + 256;   // [r][qs32|qd32]
    float* const aa = smem + L_WV + w * 768 + 512;   // [j][4]

    // ---- staging ----
    if (tid < 64) {
        const int g = b * 64 + tid;
        const float2 o2 = ((const float2*)obs2)[g];
        const float2 o1 = ((const float2*)obs1)[g];
        *(float4*)&s_obs[tid * 4] = make_float4(o2.x, o2.y, o2.x - o1.x, o2.y - o1.y);
    }
    if (HIDWS) {
        const float4* src = (const float4*)(ws + WS_HID + b * 4096);
        #pragma unroll
        for (int k = tid; k < 1024; k += 256) {
            const int row = k >> 4, c4 = (k & 15) * 4;
            const float4 v = src[k];
            *(v2f*)&s_hid[row * 66 + c4]     = vmk(v.x, v.y);
            *(v2f*)&s_hid[row * 66 + c4 + 2] = vmk(v.z, v.w);
        }
    } else {
        const int r = tid >> 2, qseg = (tid & 3) * 16;
        float acc[16];
        #pragma unroll
        for (int c = 0; c < 16; ++c) acc[c] = b_hid[qseg + c];
        for (int k = 0; k < 128; ++k) {
            const float a = hs[b * 8192 + r * 128 + k];
            #pragma unroll
            for (int c4 = 0; c4 < 4; ++c4) {
                const float4 w4 = *(const float4*)&w_hid[k * 64 + qseg + 4 * c4];
                acc[4*c4+0] = fmaf(a, w4.x, acc[4*c4+0]);
                acc[4*c4+1] = fmaf(a, w4.y, acc[4*c4+1]);
                acc[4*c4+2] = fmaf(a, w4.z, acc[4*c4+2]);
                acc[4*c4+3] = fmaf(a, w4.w, acc[4*c4+3]);
            }
        }
        #pragma unroll
        for (int c = 0; c < 16; c += 2)
            *(v2f*)&s_hid[r * 66 + qseg + c] =
                vmk(fmaxf(acc[c], 0.f), fmaxf(acc[c+1], 0.f));
    }
    __syncthreads();
    // ---- no more block barriers: wave-private phases below ----

    // ---- phase 3: cols {2l,2l+1} of [t | qs | qd] = hid[row] @ GQ + g0q ----
    {
        const v2f bias = *(const v2f*)&g0q[2 * l];
        v2f acc0 = bias, acc1 = bias, acc2 = bias, acc3 = bias;
        for (int k0 = 0; k0 < 64; k0 += 2) {
            const v2f g0 = *(const v2f*)&GQ[k0 * 128 + 2 * l];
            const v2f g1 = *(const v2f*)&GQ[(k0 + 1) * 128 + 2 * l];
            const v2f h0 = *(const v2f*)&s_hid[(rg0 + 0) * 66 + k0];
            const v2f h1 = *(const v2f*)&s_hid[(rg0 + 1) * 66 + k0];
            const v2f h2 = *(const v2f*)&s_hid[(rg0 + 2) * 66 + k0];
            const v2f h3 = *(const v2f*)&s_hid[(rg0 + 3) * 66 + k0];
            acc0 = PKFMA(vsplat(h0.x), g0, PKFMA(vsplat(h0.y), g1, acc0));
            acc1 = PKFMA(vsplat(h1.x), g0, PKFMA(vsplat(h1.y), g1, acc1));
            acc2 = PKFMA(vsplat(h2.x), g0, PKFMA(vsplat(h2.y), g1, acc2));
            acc3 = PKFMA(vsplat(h3.x), g0, PKFMA(vsplat(h3.y), g1, acc3));
        }
        if (l < 32) {
            const int c = 2 * l;
            *(v2f*)&tt[0 * 64 + c] = acc0;  *(v2f*)&tt[1 * 64 + c] = acc1;
            *(v2f*)&tt[2 * 64 + c] = acc2;  *(v2f*)&tt[3 * 64 + c] = acc3;
        } else {
            const int c = 2 * l - 64;
            *(v2f*)&qq[0 * 64 + c] = acc0;  *(v2f*)&qq[1 * 64 + c] = acc1;
            *(v2f*)&qq[2 * 64 + c] = acc2;  *(v2f*)&qq[3 * 64 + c] = acc3;
        }
    }

    // ---- phase 4: sc[r] = t[r] . hid[l] ----
    float sc[4];
    {
        v2f s0 = (v2f){0.f,0.f}, s1 = s0, s2 = s0, s3 = s0;
        const float* hl = &s_hid[l * 66];
        for (int c0 = 0; c0 < 64; c0 += 2) {
            const v2f h2 = *(const v2f*)&hl[c0];
            s0 = PKFMA(*(const v2f*)&tt[0 * 64 + c0], h2, s0);
            s1 = PKFMA(*(const v2f*)&tt[1 * 64 + c0], h2, s1);
            s2 = PKFMA(*(const v2f*)&tt[2 * 64 + c0], h2, s2);
            s3 = PKFMA(*(const v2f*)&tt[3 * 64 + c0], h2, s3);
        }
        sc[0] = s0.x + s0.y; sc[1] = s1.x + s1.y;
        sc[2] = s2.x + s2.y; sc[3] = s3.x + s3.y;
    }

    // ---- phase 5: scores + packed softmax; attn -> aa[j][4] ----
    {
        const float4 oj = *(const float4*)&s_obs[4 * l];
        float rx[4], ry[4], dx[4], dy[4];
        #pragma unroll
        for (int r = 0; r < 4; ++r) {
            const float4 oi = *(const float4*)&s_obs[4 * (rg0 + r)];
            rx[r] = oj.x - oi.x;  ry[r] = oj.y - oi.y;
            dx[r] = (oj.z - oi.z) * 4.f;  dy[r] = (oj.w - oi.w) * 4.f;
        }
        v2f acc[4] = {{0,0},{0,0},{0,0},{0,0}};
        for (int s0 = 0; s0 < 32; s0 += 2) {
            const v2f w0p = *(const v2f*)&w_sp[s0];
            const v2f w1p = *(const v2f*)&w_sp[32 + s0];
            const v2f bsp = *(const v2f*)&b_sp[s0];
            const v2f u0p = *(const v2f*)&w_vel[s0];
            const v2f u1p = *(const v2f*)&w_vel[32 + s0];
            const v2f bvp = *(const v2f*)&b_vel[s0];
            #pragma unroll
            for (int r = 0; r < 4; ++r) {
                const v2f qs2 = *(const v2f*)&qq[r * 64 + s0];
                const v2f qd2 = *(const v2f*)&qq[r * 64 + 32 + s0];
                const v2f esp = PKMAX(PKFMA(vsplat(rx[r]), w0p,
                                     PKFMA(vsplat(ry[r]), w1p, bsp)), vsplat(0.f));
                acc[r] = PKFMA(qs2, esp, acc[r]);
                const v2f edv = PKMAX(PKFMA(vsplat(dx[r]), u0p,
                                     PKFMA(vsplat(dy[r]), u1p, bvp)), vsplat(0.f));
                acc[r] = PKFMA(qd2, edv, acc[r]);
            }
        }
        const float scale = 0.08838834764831845f;  // 1/sqrt(128)
        v2f p01 = vmk((sc[0] + acc[0].x + acc[0].y) * scale,
                      (sc[1] + acc[1].x + acc[1].y) * scale);
        v2f p23 = vmk((sc[2] + acc[2].x + acc[2].y) * scale,
                      (sc[3] + acc[3].x + acc[3].y) * scale);
        v2f m01 = p01, m23 = p23;
        #pragma unroll
        for (int off = 32; off > 0; off >>= 1) {
            m01 = PKMAX(m01, shfl_xor_v2(m01, off));
            m23 = PKMAX(m23, shfl_xor_v2(m23, off));
        }
        v2f e01 = vmk(__expf(p01.x - m01.x), __expf(p01.y - m01.y));
        v2f e23 = vmk(__expf(p23.x - m23.x), __expf(p23.y - m23.y));
        v2f u01 = e01, u23 = e23;
        #pragma unroll
        for (int off = 32; off > 0; off >>= 1) {
            u01 = u01 + shfl_xor_v2(u01, off);
            u23 = u23 + shfl_xor_v2(u23, off);
        }
        *(float4*)&aa[4 * l] = make_float4(e01.x / u01.x, e01.y / u01.y,
                                           e23.x / u23.x, e23.y / u23.y);
    }

    // ---- phase 6a: pooled embeds -> tt[r] = [ssp 0..31 | sdv 32..63] ----
    {
        const int r = l >> 4, s = l & 15;   // lane covers slots {s, s+16}
        const v2f w0p = vmk(w_sp[s],        w_sp[s + 16]);
        const v2f w1p = vmk(w_sp[32 + s],   w_sp[48 + s]);
        const v2f bsp = vmk(b_sp[s],        b_sp[s + 16]);
        const v2f u0p = vmk(w_vel[s],       w_vel[s + 16]);
        const v2f u1p = vmk(w_vel[32 + s],  w_vel[48 + s]);
        const v2f bvp = vmk(b_vel[s],       b_vel[s + 16]);
        const float4 oi = *(const float4*)&s_obs[4 * (rg0 + r)];
        v2f asp = (v2f){0.f, 0.f}, adv = asp;
        for (int j = 0; j < 64; ++j) {
            const float a = aa[4 * j + r];
            const float4 o4 = *(const float4*)&s_obs[4 * j];
            const float rxx = o4.x - oi.x, ryy = o4.y - oi.y;
            const float dxx = (o4.z - oi.z) * 4.f, dyy = (o4.w - oi.w) * 4.f;
            const v2f esp = PKMAX(PKFMA(vsplat(rxx), w0p,
                                 PKFMA(vsplat(ryy), w1p, bsp)), vsplat(0.f));
            asp = PKFMA(vsplat(a), esp, asp);
            const v2f edv = PKMAX(PKFMA(vsplat(dxx), u0p,
                                 PKFMA(vsplat(dyy), u1p, bvp)), vsplat(0.f));
            adv = PKFMA(vsplat(a), edv, adv);
        }
        tt[r * 64 + s]      = asp.x;
        tt[r * 64 + s + 16] = asp.y;
        tt[r * 64 + 32 + s] = adv.x;
        tt[r * 64 + 48 + s] = adv.y;
    }

    // ---- phase 6b: ah[r][l] = attn[r] @ hid -> qq[r][l] ----
    {
        float ah0 = 0.f, ah1 = 0.f, ah2 = 0.f, ah3 = 0.f;
        for (int j = 0; j < 64; j += 2) {
            const float4 a0 = *(const float4*)&aa[4 * j];
            const float4 a1 = *(const float4*)&aa[4 * j + 4];
            const float h0 = s_hid[j * 66 + l];
            const float h1 = s_hid[(j + 1) * 66 + l];
            ah0 = fmaf(a0.x, h0, fmaf(a1.x, h1, ah0));
            ah1 = fmaf(a0.y, h0, fmaf(a1.y, h1, ah1));
            ah2 = fmaf(a0.z, h0, fmaf(a1.z, h1, ah2));
            ah3 = fmaf(a0.w, h0, fmaf(a1.w, h1, ah3));
        }
        qq[0 * 64 + l] = ah0;  qq[1 * 64 + l] = ah1;
        qq[2 * 64 + l] = ah2;  qq[3 * 64 + l] = ah3;
    }

    // ---- phase 7: out = [ssp|sdv] @ Fall[0:64] + ah @ Fall[64:128] + fb ----
    {
        const v2f fb2 = *(const v2f*)&fbv[2 * l];
        v2f o0 = fb2, o1 = fb2, o2 = fb2, o3 = fb2;
        for (int k = 0; k < 64; k += 2) {
            const v2f f0 = *(const v2f*)&Fall[k * 128 + 2 * l];
            const v2f f1 = *(const v2f*)&Fall[(k + 1) * 128 + 2 * l];
            const v2f A0 = *(const v2f*)&tt[0 * 64 + k];
            const v2f A1 = *(const v2f*)&tt[1 * 64 + k];
            const v2f A2 = *(const v2f*)&tt[2 * 64 + k];
            const v2f A3 = *(const v2f*)&tt[3 * 64 + k];
            o0 = PKFMA(vsplat(A0.x), f0, PKFMA(vsplat(A0.y), f1, o0));
            o1 = PKFMA(vsplat(A1.x), f0, PKFMA(vsplat(A1.y), f1, o1));
            o2 = PKFMA(vsplat(A2.x), f0, PKFMA(vsplat(A2.y), f1, o2));
            o3 = PKFMA(vsplat(A3.x), f0, PKFMA(vsplat(A3.y), f1, o3));
        }
        for (int k = 0; k < 64; k += 2) {
            const v2f f0 = *(const v2f*)&Fall[(64 + k) * 128 + 2 * l];
            const v2f f1 = *(const v2f*)&Fall[(65 + k) * 128 + 2 * l];
            const v2f A0 = *(const v2f*)&qq[0 * 64 + k];
            const v2f A1 = *(const v2f*)&qq[1 * 64 + k];
            const v2f A2 = *(const v2f*)&qq[2 * 64 + k];
            const v2f A3 = *(const v2f*)&qq[3 * 64 + k];
            o0 = PKFMA(vsplat(A0.x), f0, PKFMA(vsplat(A0.y), f1, o0));
            o1 = PKFMA(vsplat(A1.x), f0, PKFMA(vsplat(A1.y), f1, o1));
            o2 = PKFMA(vsplat(A2.x), f0, PKFMA(vsplat(A2.y), f1, o2));
            o3 = PKFMA(vsplat(A3.x), f0, PKFMA(vsplat(A3.y), f1, o3));
        }
        const int gr = (b * 64 + rg0) * 128 + 2 * l;
        *(v2f*)&out[gr]           = o0;
        *(v2f*)&out[gr + 128]     = o1;
        *(v2f*)&out[gr + 256]     = o2;
        *(v2f*)&out[gr + 384]     = o3;
    }
}

extern "C" void kernel_launch(void* const* d_in, const int* in_sizes, int n_in,
                              void* d_out, int out_size, void* d_ws, size_t ws_size,
                              hipStream_t stream) {
    const float* hs        = (const float*)d_in[0];
    const float* obs1      = (const float*)d_in[1];
    const float* obs2      = (const float*)d_in[2];
    const float* w_sp      = (const float*)d_in[3];
    const float* b_sp      = (const float*)d_in[4];
    const float* w_vel     = (const float*)d_in[5];
    const float* b_vel     = (const float*)d_in[6];
    const float* w_hid     = (const float*)d_in[7];
    const float* b_hid     = (const float*)d_in[8];
    const float* wq        = (const float*)d_in[9];
    const float* wk        = (const float*)d_in[10];
    const float* wv        = (const float*)d_in[11];
    const float* in_proj_w = (const float*)d_in[12];
    const float* in_proj_b = (const float*)d_in[13];
    const float* mha_out_w = (const float*)d_in[14];
    const float* mha_out_b = (const float*)d_in[15];
    const float* out_w     = (const float*)d_in[16];
    const float* out_b     = (const float*)d_in[17];
    float* ws  = (float*)d_ws;
    float* out = (float*)d_out;

    const bool hidws = (ws_size >= WS_NEED_HID_BYTES);

    precompute1<<<hidws ? 512 : 256, 256, 0, stream>>>(
        wq, wk, wv, in_proj_w, mha_out_w, out_w, hs, w_hid, b_hid, ws);
    precompute2<<<194, 128, 0, stream>>>(
        b_sp, b_vel, in_proj_b, mha_out_b, out_w, out_b, ws);
    if (hidws) {
        attn_main<true><<<512, 256, 0, stream>>>(hs, obs1, obs2, w_sp, b_sp, w_vel, b_vel,
                                                 w_hid, b_hid, ws, out);
    } else {
        attn_main<false><<<512, 256, 0, stream>>>(hs, obs1, obs2, w_sp, b_sp, w_vel, b_vel,
                                                  w_hid, b_hid, ws, out);
    }
}